// Round 11
// baseline (38.682 us; speedup 1.0000x reference)
//
#include <hip/hip_runtime.h>
#include <hip/hip_bf16.h>
#include <math.h>

// Problem: B=8, M=N=4096, C=3, f32. Avg-Hausdorff (Chamfer), out (8,).
// d2(a,b) = sa + (sb - 2 a.b); paren term = rank-16 bf16 MFMA (hi/lo split,
// validated R9, absmax 0). sa added in the final reduce (f32, R2 scheme).
constexpr int NB   = 8;
constexpr int NPTS = 4096;

typedef __attribute__((ext_vector_type(8)))  short  short8;
typedef __attribute__((ext_vector_type(16))) float  f32x16;

__device__ inline unsigned short f2bf(float v) {
    __hip_bfloat16 t = __float2bfloat16(v);
    return *reinterpret_cast<unsigned short*>(&t);
}
__device__ inline float bf2f(unsigned short u) {
    __hip_bfloat16 t = *reinterpret_cast<__hip_bfloat16*>(&u);
    return __bfloat162float(t);
}

// k0: encode panels in FRAGMENT-SLOT order: point p, half h -> short8 slot
// (p>>5)*64 + h*32 + (p&31). A wave (lane l = h*32+c) then reads tile nt as
// slots[nt*64 + l]: lane-sequential 16B -> perfectly coalesced, no LDS needed.
//  A-row: [ah.xyz al.xyz 1 1 | ah.xyz 0...]   B-row (t=-2p): [th.xyz th.xyz sqh sql | tl.xyz 0...]
__global__ __launch_bounds__(256) void prep_kernel(
    const float* __restrict__ s1, const float* __restrict__ s2,
    short8* __restrict__ Ap, short8* __restrict__ Bp, float* __restrict__ Sa)
{
    int i = blockIdx.x * 256 + threadIdx.x;      // over 2*NB*NPTS = 65536
    int s = i >> 15;
    const float* p = (s ? s2 : s1) + (size_t)(i & 32767) * 3;
    float x = p[0], y = p[1], z = p[2];
    float sq = fmaf(z, z, fmaf(y, y, x * x));

    unsigned short ahx = f2bf(x), ahy = f2bf(y), ahz = f2bf(z);
    unsigned short alx = f2bf(x - bf2f(ahx));
    unsigned short aly = f2bf(y - bf2f(ahy));
    unsigned short alz = f2bf(z - bf2f(ahz));
    unsigned short one = 0x3F80;

    float tx = -2.0f * x, ty = -2.0f * y, tz = -2.0f * z;
    unsigned short thx = f2bf(tx), thy = f2bf(ty), thz = f2bf(tz);
    unsigned short tlx = f2bf(tx - bf2f(thx));
    unsigned short tly = f2bf(ty - bf2f(thy));
    unsigned short tlz = f2bf(tz - bf2f(thz));
    unsigned short sqh = f2bf(sq);
    unsigned short sql = f2bf(sq - bf2f(sqh));

    short8 aLo = {(short)ahx,(short)ahy,(short)ahz,(short)alx,(short)aly,(short)alz,(short)one,(short)one};
    short8 aHi = {(short)ahx,(short)ahy,(short)ahz,0,0,0,0,0};
    short8 bLo = {(short)thx,(short)thy,(short)thz,(short)thx,(short)thy,(short)thz,(short)sqh,(short)sql};
    short8 bHi = {(short)tlx,(short)tly,(short)tlz,0,0,0,0,0};

    size_t slot = ((size_t)(i >> 5) << 6) + (i & 31);
    Ap[slot]      = aLo;
    Ap[slot + 32] = aHi;
    Bp[slot]      = bLo;
    Bp[slot + 32] = bHi;
    Sa[i] = sq;
}

// k1: grid = 16 g x 16 mblk x 4 nseg = 1024 blocks (4/CU, 4 waves/SIMD).
// Block: 256 m-rows x 1024 n. Wave: 2 m-tiles (64 rows). Per pair-iter:
// 2 coalesced global b128 fragment loads + 4 MFMA (C=0) + 32 fused min.
// No LDS, no barriers. Epilogue: 5-step shfl-min over n-cols -> pmin.
__global__ __launch_bounds__(256, 4) void mfma_min_kernel(
    const short8* __restrict__ Ap, const short8* __restrict__ Bp,
    float* __restrict__ pmin)
{
    int bid  = blockIdx.x;
    int nseg = bid & 3;
    int mblk = (bid >> 2) & 15;
    int g    = bid >> 6;               // dir*8 + batch
    int b    = g & 7, dir = g >> 3;
    int qs   = dir, ts = 1 - dir;

    int tid = threadIdx.x;
    int wid = tid >> 6, l = tid & 63;
    int c = l & 31, h = l >> 5;

    const short8* As = Ap + (size_t)(qs * NB + b) * NPTS * 2;
    const short8* Bs = Bp + (size_t)(ts * NB + b) * NPTS * 2 + (size_t)nseg * 2048;

    short8 afr0 = As[(mblk * 8 + wid * 2 + 0) * 64 + l];
    short8 afr1 = As[(mblk * 8 + wid * 2 + 1) * 64 + l];

    f32x16 zero, acc0, acc1;
    #pragma unroll
    for (int r = 0; r < 16; ++r) { zero[r] = 0.0f; acc0[r] = 3.4e38f; acc1[r] = 3.4e38f; }

    #pragma unroll 2
    for (int ntp = 0; ntp < 16; ++ntp) {
        short8 b0 = Bs[ntp * 128 + l];
        short8 b1 = Bs[ntp * 128 + 64 + l];
        f32x16 d0 = __builtin_amdgcn_mfma_f32_32x32x16_bf16(afr0, b0, zero, 0, 0, 0);
        f32x16 d1 = __builtin_amdgcn_mfma_f32_32x32x16_bf16(afr0, b1, zero, 0, 0, 0);
        #pragma unroll
        for (int r = 0; r < 16; ++r)
            acc0[r] = fminf(acc0[r], fminf(d0[r], d1[r]));   // v_min3
        f32x16 e0 = __builtin_amdgcn_mfma_f32_32x32x16_bf16(afr1, b0, zero, 0, 0, 0);
        f32x16 e1 = __builtin_amdgcn_mfma_f32_32x32x16_bf16(afr1, b1, zero, 0, 0, 0);
        #pragma unroll
        for (int r = 0; r < 16; ++r)
            acc1[r] = fminf(acc1[r], fminf(e0[r], e1[r]));
    }

    // Cross-lane min over the 32 n-columns (within each 32-lane half).
    int mrow0 = mblk * 256 + wid * 64;
    float* pg = pmin + ((size_t)g * 4 + nseg) * NPTS;
    #pragma unroll
    for (int mt = 0; mt < 2; ++mt) {
        #pragma unroll
        for (int r = 0; r < 16; ++r) {
            float v = (mt == 0) ? acc0[r] : acc1[r];
            v = fminf(v, __shfl_xor(v, 1, 64));
            v = fminf(v, __shfl_xor(v, 2, 64));
            v = fminf(v, __shfl_xor(v, 4, 64));
            v = fminf(v, __shfl_xor(v, 8, 64));
            v = fminf(v, __shfl_xor(v, 16, 64));
            if (c == 0) {
                int row = (r & 3) + 8 * (r >> 2) + 4 * h;
                pg[mrow0 + mt * 32 + row] = v;
            }
        }
    }
}

// k2: one block per batch (8 x 1024 thr): min over 4 nsegs, + sa, clamp,
// sqrt, both dirs, block-sum -> out[b]. Single dispatch.
__global__ __launch_bounds__(1024) void reduce_kernel(
    const float* __restrict__ pmin, const float* __restrict__ Sa,
    float* __restrict__ out)
{
    int b = blockIdx.x;
    int t = threadIdx.x;               // float4 row-group, 0..1023

    float sum = 0.0f;
    #pragma unroll
    for (int dir = 0; dir < 2; ++dir) {
        int g = dir * NB + b;
        const float4* pg = reinterpret_cast<const float4*>(pmin + (size_t)g * 4 * NPTS);
        float4 m = pg[t];
        #pragma unroll
        for (int s = 1; s < 4; ++s) {
            float4 v = pg[(size_t)s * 1024 + t];
            m.x = fminf(m.x, v.x); m.y = fminf(m.y, v.y);
            m.z = fminf(m.z, v.z); m.w = fminf(m.w, v.w);
        }
        float4 sa4 = reinterpret_cast<const float4*>(Sa + (size_t)(dir * NB + b) * NPTS)[t];
        sum += sqrtf(fmaxf(sa4.x + m.x, 0.0f)) + sqrtf(fmaxf(sa4.y + m.y, 0.0f))
             + sqrtf(fmaxf(sa4.z + m.z, 0.0f)) + sqrtf(fmaxf(sa4.w + m.w, 0.0f));
    }

    for (int off = 32; off > 0; off >>= 1)
        sum += __shfl_down(sum, off, 64);

    __shared__ float red[16];
    if ((t & 63) == 0) red[t >> 6] = sum;
    __syncthreads();
    if (t == 0) {
        float tt = 0.0f;
        #pragma unroll
        for (int w = 0; w < 16; ++w) tt += red[w];
        out[b] = tt * (1.0f / (float)NPTS);
    }
}

extern "C" void kernel_launch(void* const* d_in, const int* in_sizes, int n_in,
                              void* d_out, int out_size, void* d_ws, size_t ws_size,
                              hipStream_t stream) {
    const float* set1 = (const float*)d_in[0];
    const float* set2 = (const float*)d_in[1];
    float* out = (float*)d_out;

    char* ws = (char*)d_ws;
    short8* Ap   = (short8*)ws;                          // 2 MiB
    short8* Bp   = (short8*)(ws + (2u << 20));           // 2 MiB
    float*  Sa   = (float*)(ws + (4u << 20));            // 256 KiB
    float*  pmin = (float*)(ws + (4u << 20) + (256u << 10));  // 1 MiB

    prep_kernel<<<2 * NB * NPTS / 256, 256, 0, stream>>>(set1, set2, Ap, Bp, Sa);
    mfma_min_kernel<<<1024, 256, 0, stream>>>(Ap, Bp, pmin);
    reduce_kernel<<<NB, 1024, 0, stream>>>(pmin, Sa, out);
}

// Round 12
// 33.318 us; speedup vs baseline: 1.1610x; 1.1610x over previous
//
#include <hip/hip_runtime.h>
#include <hip/hip_bf16.h>
#include <math.h>

// Problem: B=8, M=N=4096, C=3, f32. Avg-Hausdorff (Chamfer), out (8,).
// d2(a,b) = sa + (sb - 2 a.b); paren term = rank-16 bf16 MFMA with fp32
// hi/lo splitting (validated R9/R10: absmax 0.0). sa added in k2 (f32).
constexpr int NB   = 8;
constexpr int NPTS = 4096;
constexpr int NSEG = 4;            // n segments per (dir,batch)
constexpr int NN   = NPTS / NSEG;  // 1024 n-points per block

typedef __attribute__((ext_vector_type(8)))  short  short8;
typedef __attribute__((ext_vector_type(16))) float  f32x16;

__device__ inline unsigned short f2bf(float v) {
    __hip_bfloat16 t = __float2bfloat16(v);
    return *reinterpret_cast<unsigned short*>(&t);
}
__device__ inline float bf2f(unsigned short u) {
    __hip_bfloat16 t = *reinterpret_cast<__hip_bfloat16*>(&u);
    return __bfloat162float(t);
}

// k1: grid = 16 g x 16 mblk x 4 nseg = 1024 blocks (4/CU, 4 waves/SIMD).
// Each block: encode its 1024-point B-segment into LDS in FRAGMENT-SLOT
// order (slot = (p>>5)*64 + h*32 + (p&31); lane-contiguous ds_read_b128,
// no 8-way conflicts), encode its 256 A-rows into register fragments,
// then 16 iters x {2 LDS b128 reads, 4 MFMA (C=0), 32 fused min3}.
// Epilogue: 5-step shfl-min over the 32 n-cols -> pmin[g][nseg][m].
__global__ __launch_bounds__(256, 4) void mfma_min_kernel(
    const float* __restrict__ s1, const float* __restrict__ s2,
    float* __restrict__ pmin)
{
    __shared__ short8 blds[2048];   // 32 KB, slot-ordered B fragments

    int bid  = blockIdx.x;
    int nseg = bid & 3;
    int mblk = (bid >> 2) & 15;
    int g    = bid >> 6;               // dir*8 + batch
    int b    = g & 7, dir = g >> 3;

    const float* A    = dir ? s2 : s1;   // query set
    const float* Bset = dir ? s1 : s2;   // target set

    int tid = threadIdx.x;
    int wid = tid >> 6, l = tid & 63;
    int c = l & 31, h = l >> 5;

    // ---- Encode B-segment into LDS (each thread: 4 points) ----
    const float* bsrc = Bset + ((size_t)b * NPTS + (size_t)nseg * NN) * 3;
    #pragma unroll
    for (int k = 0; k < 4; ++k) {
        int p = k * 256 + tid;           // 0..1023
        float x = bsrc[p*3+0], y = bsrc[p*3+1], z = bsrc[p*3+2];
        float sq = fmaf(z, z, fmaf(y, y, x * x));
        float tx = -2.0f*x, ty = -2.0f*y, tz = -2.0f*z;
        unsigned short thx = f2bf(tx), thy = f2bf(ty), thz = f2bf(tz);
        unsigned short tlx = f2bf(tx - bf2f(thx));
        unsigned short tly = f2bf(ty - bf2f(thy));
        unsigned short tlz = f2bf(tz - bf2f(thz));
        unsigned short sqh = f2bf(sq);
        unsigned short sql = f2bf(sq - bf2f(sqh));
        short8 bLo = {(short)thx,(short)thy,(short)thz,(short)thx,(short)thy,(short)thz,(short)sqh,(short)sql};
        short8 bHi = {(short)tlx,(short)tly,(short)tlz,0,0,0,0,0};
        int slot = (p >> 5) * 64 + (p & 31);
        blds[slot]      = bLo;
        blds[slot + 32] = bHi;
    }

    // ---- Encode this wave's 2 A-fragments (64 m-rows) in registers ----
    short8 afr[2];
    #pragma unroll
    for (int mt = 0; mt < 2; ++mt) {
        int arow = mblk * 256 + wid * 64 + mt * 32 + c;
        const float* ap = A + ((size_t)b * NPTS + arow) * 3;
        float x = ap[0], y = ap[1], z = ap[2];
        unsigned short ahx = f2bf(x), ahy = f2bf(y), ahz = f2bf(z);
        if (h == 0) {
            unsigned short alx = f2bf(x - bf2f(ahx));
            unsigned short aly = f2bf(y - bf2f(ahy));
            unsigned short alz = f2bf(z - bf2f(ahz));
            unsigned short one = 0x3F80;
            afr[mt] = short8{(short)ahx,(short)ahy,(short)ahz,
                             (short)alx,(short)aly,(short)alz,(short)one,(short)one};
        } else {
            afr[mt] = short8{(short)ahx,(short)ahy,(short)ahz,0,0,0,0,0};
        }
    }
    __syncthreads();

    f32x16 zero, acc0, acc1;
    #pragma unroll
    for (int r = 0; r < 16; ++r) { zero[r] = 0.0f; acc0[r] = 3.4e38f; acc1[r] = 3.4e38f; }

    #pragma unroll 2
    for (int ntp = 0; ntp < 16; ++ntp) {       // 32 n-tiles, in pairs
        short8 b0 = blds[ntp * 128 + l];        // lane-contiguous 16B reads
        short8 b1 = blds[ntp * 128 + 64 + l];
        f32x16 d0 = __builtin_amdgcn_mfma_f32_32x32x16_bf16(afr[0], b0, zero, 0, 0, 0);
        f32x16 d1 = __builtin_amdgcn_mfma_f32_32x32x16_bf16(afr[0], b1, zero, 0, 0, 0);
        #pragma unroll
        for (int r = 0; r < 16; ++r)
            acc0[r] = fminf(acc0[r], fminf(d0[r], d1[r]));   // v_min3
        f32x16 e0 = __builtin_amdgcn_mfma_f32_32x32x16_bf16(afr[1], b0, zero, 0, 0, 0);
        f32x16 e1 = __builtin_amdgcn_mfma_f32_32x32x16_bf16(afr[1], b1, zero, 0, 0, 0);
        #pragma unroll
        for (int r = 0; r < 16; ++r)
            acc1[r] = fminf(acc1[r], fminf(e0[r], e1[r]));
    }

    // ---- Cross-lane min over the 32 n-columns, store row-mins ----
    int mrow0 = mblk * 256 + wid * 64;
    float* pg = pmin + ((size_t)g * NSEG + nseg) * NPTS;
    #pragma unroll
    for (int mt = 0; mt < 2; ++mt) {
        #pragma unroll
        for (int r = 0; r < 16; ++r) {
            float v = (mt == 0) ? acc0[r] : acc1[r];
            v = fminf(v, __shfl_xor(v, 1, 64));
            v = fminf(v, __shfl_xor(v, 2, 64));
            v = fminf(v, __shfl_xor(v, 4, 64));
            v = fminf(v, __shfl_xor(v, 8, 64));
            v = fminf(v, __shfl_xor(v, 16, 64));
            if (c == 0) {
                int row = (r & 3) + 8 * (r >> 2) + 4 * h;
                pg[mrow0 + mt * 32 + row] = v;
            }
        }
    }
}

// k2: one block per batch (8 x 1024 thr). Per thread: 4 query points;
// min over 4 nsegs (float4, coalesced), + sa computed from raw input,
// clamp, sqrt; both dirs; block-sum -> out[b].
__global__ __launch_bounds__(1024) void reduce_kernel(
    const float* __restrict__ s1, const float* __restrict__ s2,
    const float* __restrict__ pmin, float* __restrict__ out)
{
    int b = blockIdx.x;
    int t = threadIdx.x;               // float4 row-group, 0..1023

    float sum = 0.0f;
    #pragma unroll
    for (int dir = 0; dir < 2; ++dir) {
        int g = dir * NB + b;
        const float4* pg = reinterpret_cast<const float4*>(pmin + (size_t)g * NSEG * NPTS);
        float4 m = pg[t];
        #pragma unroll
        for (int s = 1; s < NSEG; ++s) {
            float4 v = pg[(size_t)s * 1024 + t];
            m.x = fminf(m.x, v.x); m.y = fminf(m.y, v.y);
            m.z = fminf(m.z, v.z); m.w = fminf(m.w, v.w);
        }
        // sa for query points 4t..4t+3 from the raw set (12 floats).
        const float* q = (dir ? s2 : s1) + ((size_t)b * NPTS + (size_t)4 * t) * 3;
        const float4* q4 = reinterpret_cast<const float4*>(q);
        float4 f0 = q4[0], f1 = q4[1], f2 = q4[2];
        float sa0 = fmaf(f0.z, f0.z, fmaf(f0.y, f0.y, f0.x * f0.x));
        float sa1 = fmaf(f1.y, f1.y, fmaf(f1.x, f1.x, f0.w * f0.w));
        float sa2 = fmaf(f2.x, f2.x, fmaf(f1.w, f1.w, f1.z * f1.z));
        float sa3 = fmaf(f2.w, f2.w, fmaf(f2.z, f2.z, f2.y * f2.y));
        sum += sqrtf(fmaxf(sa0 + m.x, 0.0f)) + sqrtf(fmaxf(sa1 + m.y, 0.0f))
             + sqrtf(fmaxf(sa2 + m.z, 0.0f)) + sqrtf(fmaxf(sa3 + m.w, 0.0f));
    }

    for (int off = 32; off > 0; off >>= 1)
        sum += __shfl_down(sum, off, 64);

    __shared__ float red[16];
    if ((t & 63) == 0) red[t >> 6] = sum;
    __syncthreads();
    if (t == 0) {
        float tt = 0.0f;
        #pragma unroll
        for (int w = 0; w < 16; ++w) tt += red[w];
        out[b] = tt * (1.0f / (float)NPTS);
    }
}

extern "C" void kernel_launch(void* const* d_in, const int* in_sizes, int n_in,
                              void* d_out, int out_size, void* d_ws, size_t ws_size,
                              hipStream_t stream) {
    const float* set1 = (const float*)d_in[0];
    const float* set2 = (const float*)d_in[1];
    float* out  = (float*)d_out;
    float* pmin = (float*)d_ws;    // 2*NB*NSEG*NPTS*4 = 1 MiB

    mfma_min_kernel<<<16 * 16 * NSEG, 256, 0, stream>>>(set1, set2, pmin);
    reduce_kernel<<<NB, 1024, 0, stream>>>(set1, set2, pmin, out);
}

// Round 13
// 18.325 us; speedup vs baseline: 2.1109x; 1.8182x over previous
//
#include <hip/hip_runtime.h>
#include <hip/hip_bf16.h>
#include <math.h>

// Problem: B=8, M=N=4096, C=3, f32. Avg-Hausdorff (Chamfer), out (8,).
// d2(a,b) = sa + (sb - 2 a.b); paren term = rank-16 bf16 MFMA with fp32
// hi/lo splitting (validated R9-R11: absmax 0.0). sa added in k2 (f32).
//
// R12 structural fix: MFMA operands SWAPPED -> D = Target x Query, so each
// lane's 16 accumulator entries belong to ONE query column; the min over
// target points is lane-local (v_min per iter + 15-op fold + 1 shfl at end)
// instead of 160 cross-lane shuffles per wave (R9/R11 epilogue).
constexpr int NB   = 8;
constexpr int NPTS = 4096;
constexpr int NSEG = 4;            // n segments per (dir,batch)
constexpr int NN   = NPTS / NSEG;  // 1024 target points per block

typedef __attribute__((ext_vector_type(8)))  short  short8;
typedef __attribute__((ext_vector_type(16))) float  f32x16;

__device__ inline unsigned short f2bf(float v) {
    __hip_bfloat16 t = __float2bfloat16(v);
    return *reinterpret_cast<unsigned short*>(&t);
}
__device__ inline float bf2f(unsigned short u) {
    __hip_bfloat16 t = *reinterpret_cast<__hip_bfloat16*>(&u);
    return __bfloat162float(t);
}

// k1: grid = 16 g x 16 qblk x 4 nseg = 1024 blocks (4/CU, 4 waves/SIMD).
// Block: 256 query rows x 1024 target points. Wave: 2 query fragments
// (64 queries). Per iter: 2 LDS target-tile reads + 4 MFMA(T,Q) + 32 min3.
// Target fragments staged in LDS in slot order (lane-contiguous b128).
__global__ __launch_bounds__(256, 4) void mfma_min_kernel(
    const float* __restrict__ s1, const float* __restrict__ s2,
    float* __restrict__ pmin)
{
    __shared__ short8 blds[2048];   // 32 KB, slot-ordered target fragments

    int bid  = blockIdx.x;
    int nseg = bid & 3;
    int qb   = (bid >> 2) & 15;
    int g    = bid >> 6;               // dir*8 + batch
    int b    = g & 7, dir = g >> 3;

    const float* Q    = dir ? s2 : s1;   // query set
    const float* Tset = dir ? s1 : s2;   // target set

    int tid = threadIdx.x;
    int wid = tid >> 6, l = tid & 63;
    int c = l & 31, h = l >> 5;

    // ---- Encode target segment into LDS (each thread: 4 points) ----
    const float* tsrc = Tset + ((size_t)b * NPTS + (size_t)nseg * NN) * 3;
    #pragma unroll
    for (int k = 0; k < 4; ++k) {
        int p = k * 256 + tid;           // 0..1023
        float x = tsrc[p*3+0], y = tsrc[p*3+1], z = tsrc[p*3+2];
        float sq = fmaf(z, z, fmaf(y, y, x * x));
        float tx = -2.0f*x, ty = -2.0f*y, tz = -2.0f*z;
        unsigned short thx = f2bf(tx), thy = f2bf(ty), thz = f2bf(tz);
        unsigned short tlx = f2bf(tx - bf2f(thx));
        unsigned short tly = f2bf(ty - bf2f(thy));
        unsigned short tlz = f2bf(tz - bf2f(thz));
        unsigned short sqh = f2bf(sq);
        unsigned short sql = f2bf(sq - bf2f(sqh));
        short8 tLo = {(short)thx,(short)thy,(short)thz,(short)thx,(short)thy,(short)thz,(short)sqh,(short)sql};
        short8 tHi = {(short)tlx,(short)tly,(short)tlz,0,0,0,0,0};
        int slot = (p >> 5) * 64 + (p & 31);
        blds[slot]      = tLo;
        blds[slot + 32] = tHi;
    }

    // ---- Encode this wave's 2 query fragments (64 queries) ----
    short8 qfr[2];
    #pragma unroll
    for (int f = 0; f < 2; ++f) {
        int qidx = qb * 256 + wid * 64 + f * 32 + c;
        const float* qp = Q + ((size_t)b * NPTS + qidx) * 3;
        float x = qp[0], y = qp[1], z = qp[2];
        unsigned short ahx = f2bf(x), ahy = f2bf(y), ahz = f2bf(z);
        if (h == 0) {
            unsigned short alx = f2bf(x - bf2f(ahx));
            unsigned short aly = f2bf(y - bf2f(ahy));
            unsigned short alz = f2bf(z - bf2f(ahz));
            unsigned short one = 0x3F80;
            qfr[f] = short8{(short)ahx,(short)ahy,(short)ahz,
                            (short)alx,(short)aly,(short)alz,(short)one,(short)one};
        } else {
            qfr[f] = short8{(short)ahx,(short)ahy,(short)ahz,0,0,0,0,0};
        }
    }
    __syncthreads();

    f32x16 zero, acc0, acc1;
    #pragma unroll
    for (int r = 0; r < 16; ++r) { zero[r] = 0.0f; acc0[r] = 3.4e38f; acc1[r] = 3.4e38f; }

    #pragma unroll 2
    for (int ntp = 0; ntp < 16; ++ntp) {       // 32 target tiles, in pairs
        short8 t0 = blds[(2*ntp  ) * 64 + l];   // lane-contiguous b128
        short8 t1 = blds[(2*ntp+1) * 64 + l];
        // D = Target x Query: col (lane&31) = query, rows = target points.
        f32x16 d0 = __builtin_amdgcn_mfma_f32_32x32x16_bf16(t0, qfr[0], zero, 0, 0, 0);
        f32x16 d1 = __builtin_amdgcn_mfma_f32_32x32x16_bf16(t1, qfr[0], zero, 0, 0, 0);
        #pragma unroll
        for (int r = 0; r < 16; ++r)
            acc0[r] = fminf(fminf(acc0[r], d0[r]), d1[r]);   // v_min3
        f32x16 e0 = __builtin_amdgcn_mfma_f32_32x32x16_bf16(t0, qfr[1], zero, 0, 0, 0);
        f32x16 e1 = __builtin_amdgcn_mfma_f32_32x32x16_bf16(t1, qfr[1], zero, 0, 0, 0);
        #pragma unroll
        for (int r = 0; r < 16; ++r)
            acc1[r] = fminf(fminf(acc1[r], e0[r]), e1[r]);
    }

    // ---- Lane-local fold (15 min) + 1 cross-half shuffle; store query-min.
    float* pg = pmin + ((size_t)g * NSEG + nseg) * NPTS;
    #pragma unroll
    for (int f = 0; f < 2; ++f) {
        f32x16& a = f ? acc1 : acc0;
        float v = a[0];
        #pragma unroll
        for (int r = 1; r < 16; ++r) v = fminf(v, a[r]);
        v = fminf(v, __shfl_xor(v, 32, 64));   // combine h halves (disjoint rows)
        if (h == 0)
            pg[qb * 256 + wid * 64 + f * 32 + c] = v;   // 128B coalesced
    }
}

// k2: one block per batch (8 x 1024 thr). Per thread: 4 query points;
// min over 4 nsegs (float4, coalesced), + sa computed from raw input,
// clamp, sqrt; both dirs; block-sum -> out[b]. (Validated R11.)
__global__ __launch_bounds__(1024) void reduce_kernel(
    const float* __restrict__ s1, const float* __restrict__ s2,
    const float* __restrict__ pmin, float* __restrict__ out)
{
    int b = blockIdx.x;
    int t = threadIdx.x;               // float4 row-group, 0..1023

    float sum = 0.0f;
    #pragma unroll
    for (int dir = 0; dir < 2; ++dir) {
        int g = dir * NB + b;
        const float4* pg = reinterpret_cast<const float4*>(pmin + (size_t)g * NSEG * NPTS);
        float4 m = pg[t];
        #pragma unroll
        for (int s = 1; s < NSEG; ++s) {
            float4 v = pg[(size_t)s * 1024 + t];
            m.x = fminf(m.x, v.x); m.y = fminf(m.y, v.y);
            m.z = fminf(m.z, v.z); m.w = fminf(m.w, v.w);
        }
        const float* q = (dir ? s2 : s1) + ((size_t)b * NPTS + (size_t)4 * t) * 3;
        const float4* q4 = reinterpret_cast<const float4*>(q);
        float4 f0 = q4[0], f1 = q4[1], f2 = q4[2];
        float sa0 = fmaf(f0.z, f0.z, fmaf(f0.y, f0.y, f0.x * f0.x));
        float sa1 = fmaf(f1.y, f1.y, fmaf(f1.x, f1.x, f0.w * f0.w));
        float sa2 = fmaf(f2.x, f2.x, fmaf(f1.w, f1.w, f1.z * f1.z));
        float sa3 = fmaf(f2.w, f2.w, fmaf(f2.z, f2.z, f2.y * f2.y));
        sum += sqrtf(fmaxf(sa0 + m.x, 0.0f)) + sqrtf(fmaxf(sa1 + m.y, 0.0f))
             + sqrtf(fmaxf(sa2 + m.z, 0.0f)) + sqrtf(fmaxf(sa3 + m.w, 0.0f));
    }

    for (int off = 32; off > 0; off >>= 1)
        sum += __shfl_down(sum, off, 64);

    __shared__ float red[16];
    if ((t & 63) == 0) red[t >> 6] = sum;
    __syncthreads();
    if (t == 0) {
        float tt = 0.0f;
        #pragma unroll
        for (int w = 0; w < 16; ++w) tt += red[w];
        out[b] = tt * (1.0f / (float)NPTS);
    }
}

extern "C" void kernel_launch(void* const* d_in, const int* in_sizes, int n_in,
                              void* d_out, int out_size, void* d_ws, size_t ws_size,
                              hipStream_t stream) {
    const float* set1 = (const float*)d_in[0];
    const float* set2 = (const float*)d_in[1];
    float* out  = (float*)d_out;
    float* pmin = (float*)d_ws;    // 2*NB*NSEG*NPTS*4 = 1 MiB

    mfma_min_kernel<<<16 * 16 * NSEG, 256, 0, stream>>>(set1, set2, pmin);
    reduce_kernel<<<NB, 1024, 0, stream>>>(set1, set2, pmin, out);
}